// Round 10
// baseline (355.279 us; speedup 1.0000x reference)
//
#include <hip/hip_runtime.h>
#include <math.h>

// Problem constants
#define TT   52        // time steps
#define BBAT 4         // batch
#define CCH  9         // input channels
#define HWP  4096      // 64*64 pixels per image
#define FF   64        // features
#define NP   16384     // b*h*w pixels
#define TD   5         // theta dim
#define NCC  6         // tessellation cells
#define TSTRIDE 147456 // b*c*h*w (stride of t in x, floats)

// output offsets (floats)
#define OUT0 0
#define OUT1 (NP*CCH*TT)        // x_shift_pix
#define OUT2 (2*NP*CCH*TT)      // theta_pred
#define OUT3 (OUT2 + NP*TD)     // theta_shift

// workspace offsets (floats)
#define WS_BF    0      // 60 floats: CPAB basis
#define WS_WIMG  1024   // 12*64 int4: w1a/w2a fragment image
#define WS_AIMG  4096   // 8*32*64 int4 = 65536 floats: fc1w A-fragment image
#define WS_XPIX  69632  // NP*CCH*TT floats: x pixel-major [n][c][t] (optional)

typedef __attribute__((ext_vector_type(8)))  short short8v;
typedef __attribute__((ext_vector_type(4)))  float f32x4;
typedef __attribute__((ext_vector_type(4)))  int   int4v;
typedef __attribute__((ext_vector_type(2)))  int   int2v;

// RNE f32->bf16 bits, packed pair (scalar fallback, prep kernels)
__device__ __forceinline__ unsigned bfb(float f) {
    unsigned x = __builtin_bit_cast(unsigned, f);
    return (x + 0x7fffu + ((x >> 16) & 1u)) >> 16;
}
__device__ __forceinline__ unsigned pk2(float a, float b) {
    return bfb(a) | (bfb(b) << 16);
}
// HW packed convert (1 VALU op): D.lo = bf16(a), D.hi = bf16(b)
__device__ __forceinline__ unsigned cvtpk(float a, float b) {
    unsigned r;
    asm("v_cvt_pk_bf16_f32 %0, %1, %2" : "=v"(r) : "v"(a), "v"(b));
    return r;
}
// zP row-XOR helper
__device__ __forceinline__ int nswz(int n) {
    return (((n ^ (n >> 3)) & 1) << 6) | (((n >> 1) & 3) << 4);
}

// ---------------------------------------------------------------------------
// k_pre: merged prep. block 0: basis (wave 0) + conv fragments (wave 1);
// blocks 1..64: fc1w A-fragment image; blocks 65..2368: x -> xp transpose.
// ---------------------------------------------------------------------------
__global__ __launch_bounds__(256) void k_pre(
    const float* __restrict__ lniw, const float* __restrict__ lnib,
    const float* __restrict__ w1c,  const float* __restrict__ b1c,
    const float* __restrict__ w2c,  const float* __restrict__ fc1w,
    const float* __restrict__ x,
    float* __restrict__ Bout, int4v* __restrict__ wimg,
    int4v* __restrict__ aimg, float* __restrict__ xp, int use_xp)
{
    __shared__ float ld[52 * 65];
    int blk = blockIdx.x;
    int tid = threadIdx.x;

    if (blk == 0) {
        if (tid < 64) {
            // ---- basis: np.linalg.svd(L) null-space (dgesdd LQ path) ----
            int k = tid;
            double Acol[7], Vcol[7], Mcol[5];
#pragma unroll
            for (int r = 0; r < 7; r++) { Acol[r] = 0.0; Vcol[r] = 0.0; }
#pragma unroll
            for (int j = 0; j < 5; j++) Mcol[j] = 0.0;
            if (k < 12) {
#pragma unroll
                for (int j = 1; j < 6; j++) {
                    int r = j - 1;
                    double xj = (double)j / 6.0;
                    if (k == 2 * (j - 1))     Acol[r] = xj;
                    if (k == 2 * (j - 1) + 1) Acol[r] = 1.0;
                    if (k == 2 * j)           Acol[r] = -xj;
                    if (k == 2 * j + 1)       Acol[r] = -1.0;
                }
                if (k == 1)  Acol[5] = 1.0;
                if (k == 10) Acol[6] = 1.0;
                if (k == 11) Acol[6] = 1.0;
#pragma unroll
                for (int j = 0; j < 5; j++) Mcol[j] = (k == 7 + j) ? 1.0 : 0.0;
            }
            double tau[7];
#pragma unroll
            for (int i = 0; i < 7; i++) {
                double c = (k > i && k < 12) ? Acol[i] * Acol[i] : 0.0;
#pragma unroll
                for (int off = 1; off < 64; off <<= 1) c += __shfl_xor(c, off, 64);
                double alpha = __shfl(Acol[i], i, 64);
                double t_i, vk;
                if (c == 0.0) {
                    t_i = 0.0;
                    vk = (k == i) ? 1.0 : 0.0;
                } else {
                    double nrm  = sqrt(alpha * alpha + c);
                    double beta = (alpha >= 0.0) ? -nrm : nrm;  // Fortran SIGN
                    t_i = (beta - alpha) / beta;
                    double inv = 1.0 / (alpha - beta);
                    vk = (k == i) ? 1.0 : ((k > i && k < 12) ? Acol[i] * inv : 0.0);
                }
                tau[i]  = t_i;
                Vcol[i] = vk;
#pragma unroll
                for (int r = 0; r < 7; r++) {
                    if (r > i) {
                        double w = Acol[r] * vk;
#pragma unroll
                        for (int off = 1; off < 64; off <<= 1) w += __shfl_xor(w, off, 64);
                        Acol[r] -= t_i * w * vk;
                    }
                }
            }
#pragma unroll
            for (int i = 6; i >= 0; i--) {
#pragma unroll
                for (int j = 0; j < 5; j++) {
                    double w = Mcol[j] * Vcol[i];
#pragma unroll
                    for (int off = 1; off < 64; off <<= 1) w += __shfl_xor(w, off, 64);
                    Mcol[j] -= tau[i] * w * Vcol[i];
                }
            }
            if (k < 12) {
#pragma unroll
                for (int j = 0; j < 5; j++) Bout[k * 5 + j] = (float)Mcol[j];
            }
        } else if (tid < 128) {
            // ---- conv1/conv2 MFMA A-fragments -> wimg ----
            int lane = tid - 64;
            int pl = lane & 15, h = lane >> 4;
#pragma unroll
            for (int mt = 0; mt < 4; ++mt) {
                int f = mt * 16 + pl;
                float b0f = b1c[f];
#pragma unroll
                for (int c = 0; c < 9; ++c) b0f += lnib[c] * w1c[c * 64 + f];
                float v[8];
#pragma unroll
                for (int i = 0; i < 8; ++i) {
                    int c  = h * 8 + i;
                    int cc = c < 9 ? c : 8;
                    float lv = lniw[cc] * w1c[cc * 64 + f];
                    v[i] = (c < 9) ? lv : ((c == 9) ? b0f : 0.f);
                }
                wimg[mt * 64 + lane] = (int4v){(int)pk2(v[0],v[1]), (int)pk2(v[2],v[3]),
                                               (int)pk2(v[4],v[5]), (int)pk2(v[6],v[7])};
            }
#pragma unroll
            for (int mt2 = 0; mt2 < 4; ++mt2) {
                int g = mt2 * 16 + pl;
#pragma unroll
                for (int ks = 0; ks < 2; ++ks) {
                    float v[8];
#pragma unroll
                    for (int i = 0; i < 8; ++i) v[i] = w2c[(ks * 32 + h * 8 + i) * 64 + g];
                    wimg[(4 + mt2 * 2 + ks) * 64 + lane] =
                        (int4v){(int)pk2(v[0],v[1]), (int)pk2(v[2],v[3]),
                                (int)pk2(v[4],v[5]), (int)pk2(v[6],v[7])};
                }
            }
        }
    } else if (blk <= 64) {
        // ---- fc1w -> bf16 A-fragment image ----
        int gid  = (blk - 1) * 256 + tid;
        int lane = gid & 63;
        int tc   = gid >> 6;
        int t = tc >> 5, c = tc & 31;
        int bt = t >> 2, tt0 = (t & 3) << 4;
        int m = lane & 15, h = lane >> 4;
        float v[8];
#pragma unroll
        for (int i = 0; i < 8; ++i) {
            int k = c * 32 + h * 8 + i;
            int pos_l = k >> 6, g = k & 63;
            int tt = tt0 + pos_l;
            v[i] = (tt < 52) ? fc1w[(bt * 3328 + g * 52 + tt) * 16 + m] : 0.f;
        }
        aimg[gid] = (int4v){(int)pk2(v[0],v[1]), (int)pk2(v[2],v[3]),
                            (int)pk2(v[4],v[5]), (int)pk2(v[6],v[7])};
    } else if (use_xp) {
        // ---- x [t,b,c,h,w] -> xp [n][c][t], LDS-tiled transpose ----
        int b2 = blk - 65;
        int b = b2 / 576, rem = b2 % 576, c = rem >> 6, pt = rem & 63;
        int p0 = pt * 64;
        for (int idx = tid; idx < 52 * 64; idx += 256) {
            int t = idx >> 6, pp = idx & 63;
            ld[t * 65 + pp] = x[((t * BBAT + b) * CCH + c) * HWP + p0 + pp];
        }
        __syncthreads();
        int pn = tid >> 2, tq = tid & 3;
        float* dst = xp + (size_t)(b * HWP + p0 + pn) * (CCH * TT) + c * TT + tq * 13;
#pragma unroll
        for (int k = 0; k < 13; ++k) dst[k] = ld[(tq * 13 + k) * 65 + pn];
    }
}

// ---------------------------------------------------------------------------
// k_cpab: ODE + lerp (pixel-major xp when available); optionally also emits
// theta_shift = 0.5*raw (fused former k_theta_shift).
// ---------------------------------------------------------------------------
__global__ __launch_bounds__(256) void k_cpab(
    const float* __restrict__ x, const float* __restrict__ xp, int use_xp,
    const float* __restrict__ theta, const float* __restrict__ Bf,
    float scale, float* __restrict__ out,
    float* __restrict__ outts, int do_ts)
{
    int gid = blockIdx.x * blockDim.x + threadIdx.x;
    if (gid >= NP * TT) return;
    if (do_ts && gid < NP * TD) outts[gid] = 0.5f * theta[gid];
    int n = gid / TT, tt = gid % TT;

    float th[TD];
#pragma unroll
    for (int j = 0; j < TD; j++) th[j] = scale * theta[n * TD + j];

    float a[NCC], b[NCC];
#pragma unroll
    for (int i = 0; i < NCC; i++) {
        float aa = 0.f, bb = 0.f;
#pragma unroll
        for (int j = 0; j < TD; j++) {
            aa += th[j] * Bf[(2 * i) * TD + j];
            bb += th[j] * Bf[(2 * i + 1) * TD + j];
        }
        a[i] = aa; b[i] = bb;
    }

    float xc = (float)tt / 51.0f;
    for (int s = 0; s < 100; ++s) {
        float t6 = xc * 6.0f;
        float av = t6 < 1.f ? a[0] : t6 < 2.f ? a[1] : t6 < 3.f ? a[2]
                 : t6 < 4.f ? a[3] : t6 < 5.f ? a[4] : a[5];
        float bv = t6 < 1.f ? b[0] : t6 < 2.f ? b[1] : t6 < 3.f ? b[2]
                 : t6 < 4.f ? b[3] : t6 < 5.f ? b[4] : b[5];
        xc = xc + 0.01f * (av * xc + bv);
        xc = fminf(fmaxf(xc, 0.0f), 1.0f);
    }

    float pos = xc * 51.0f;
    int x0 = (int)floorf(pos);
    if (x0 < 0) x0 = 0;
    if (x0 > 50) x0 = 50;
    float w = pos - (float)x0;
    if (use_xp) {
        const float* row = xp + (size_t)n * (CCH * TT);
#pragma unroll
        for (int ch = 0; ch < CCH; ++ch) {
            float d0 = row[ch * TT + x0];
            float d1 = row[ch * TT + x0 + 1];
            out[n * (CCH * TT) + ch * TT + tt] = d0 * (1.0f - w) + d1 * w;
        }
    } else {
        int bb_ = n >> 12, p = n & 4095;
        int base0 = ((x0 * BBAT + bb_) * CCH) * HWP + p;
#pragma unroll
        for (int ch = 0; ch < CCH; ++ch) {
            float d0 = x[base0 + ch * HWP];
            float d1 = x[base0 + ch * HWP + TSTRIDE];
            out[n * (CCH * TT) + ch * TT + tt] = d0 * (1.0f - w) + d1 * w;
        }
    }
}

// ---------------------------------------------------------------------------
// k_loc (full-MFMA, 16 px / 8 waves / 512 threads): conv subs = 2 per wave,
// fc1 chunks = 4 per wave. LDS 61KB -> 2 blocks/CU = 16 waves/CU (50% occ),
// half the per-wave serial chain of round 9. bf16 packing via HW cvt_pk.
// ---------------------------------------------------------------------------
__global__ __launch_bounds__(512, 4) void k_loc(
    const float* __restrict__ x,     // [52,4,9,64,64]
    const float* __restrict__ xs,    // x_shift_pix [N,9,52]
    const int4v* __restrict__ wimg,  // conv fragment image
    const int4v* __restrict__ aimg,  // fc1w A-fragment image
    const float* __restrict__ b2c,
    const float* __restrict__ lncw,  const float* __restrict__ lncb,
    const float* __restrict__ fc1b,
    const float* __restrict__ fc2w,  const float* __restrict__ fc2b,
    float* __restrict__ outtheta)    // [N,5]
{
    __shared__ int4v          zcs[256];        // 4KB  zc lo-8 per (px,pos), swizzled
    __shared__ unsigned       zchs[256];       // 1KB  pk2(c8, bias)
    __shared__ unsigned short y1b[8][16][64];  // 16KB per-wave y1 tile
    __shared__ unsigned short zP[16][1024];    // 32KB z2 [px][k], swizzled
    __shared__ float          dred[8][16][16]; // 8KB  [wave][px][j]

    int tid    = threadIdx.x;
    int lane   = tid & 63;
    int wv     = tid >> 6;          // 0..7
    int base16 = blockIdx.x * 16;
    int bb_    = base16 >> 12, p0 = base16 & 4095;
    int pl     = lane & 15;
    int h      = lane >> 4;

    // ---- fragments (coalesced b128 from wimg) ----
    short8v w1a[4], w2a[4][2];
#pragma unroll
    for (int mt = 0; mt < 4; ++mt)
        w1a[mt] = __builtin_bit_cast(short8v, wimg[mt * 64 + lane]);
#pragma unroll
    for (int mt2 = 0; mt2 < 4; ++mt2)
#pragma unroll
        for (int ks = 0; ks < 2; ++ks)
            w2a[mt2][ks] = __builtin_bit_cast(short8v, wimg[(4 + mt2 * 2 + ks) * 64 + lane]);

    f32x4 b2v[4], lw4[4], lb4[4];
#pragma unroll
    for (int mt2 = 0; mt2 < 4; ++mt2) {
        b2v[mt2] = *(const f32x4*)(b2c  + mt2 * 16 + h * 4);
        lw4[mt2] = *(const f32x4*)(lncw + mt2 * 16 + h * 4);
        lb4[mt2] = *(const f32x4*)(lncb + mt2 * 16 + h * 4);
    }

    f32x4 dacc = (f32x4){0.f, 0.f, 0.f, 0.f};

    for (int t = 0; t < 8; ++t) {
        int bt = t >> 2, tt0 = (t & 3) << 4;

        // ---- LN9 stage (first 4 waves; one (px,pos) per thread) ----
        if (tid < 256) {
            int px, q;
            if (bt == 0) { px = tid & 15; q = tid >> 4; }   // lanes = px (coalesced)
            else         { px = tid >> 4; q = tid & 15; }   // lanes = tt (row-coalesced)
            int tt = tt0 + q;
            float zc[9], bias;
            if (tt < 52) {
                float xin[9];
                if (bt == 0) {
                    int base = ((tt * BBAT + bb_) * CCH) * HWP + p0 + px;
#pragma unroll
                    for (int c = 0; c < 9; ++c) xin[c] = x[base + c * HWP];
                } else {
                    int base = (base16 + px) * (CCH * TT) + tt;
#pragma unroll
                    for (int c = 0; c < 9; ++c) xin[c] = xs[base + c * TT];
                }
                float s1 = 0.f, s2 = 0.f;
#pragma unroll
                for (int c = 0; c < 9; ++c) { s1 += xin[c]; s2 += xin[c] * xin[c]; }
                float m  = s1 * (1.0f / 9.0f);
                float vv = fmaxf(s2 * (1.0f / 9.0f) - m * m, 0.f);
                float rs = rsqrtf(vv + 1e-5f);
#pragma unroll
                for (int c = 0; c < 9; ++c) zc[c] = (xin[c] - m) * rs;
                bias = 1.0f;
            } else {
#pragma unroll
                for (int c = 0; c < 9; ++c) zc[c] = 0.f;
                bias = 0.f;
            }
            zcs[px * 16 + (q ^ (px & 7))] =
                (int4v){(int)cvtpk(zc[0], zc[1]), (int)cvtpk(zc[2], zc[3]),
                        (int)cvtpk(zc[4], zc[5]), (int)cvtpk(zc[6], zc[7])};
            zchs[px * 16 + q] = cvtpk(zc[8], bias);
        }
        __syncthreads();

        // ---- conv: 2 pixels per wave ----
        int sw = (pl & 7) << 3;
#pragma unroll
        for (int sub = 0; sub < 2; ++sub) {
            int px = wv * 2 + sub;
            int nswp = nswz(px);

            short8v b1f;
            if (h == 1) {
                unsigned zv = zchs[px * 16 + pl];
                b1f = __builtin_bit_cast(short8v, (int4v){(int)zv, 0, 0, 0});
            } else {
                b1f = __builtin_bit_cast(short8v, zcs[px * 16 + (pl ^ (px & 7))]);
            }

#pragma unroll
            for (int mt = 0; mt < 4; ++mt) {
                f32x4 c1 = __builtin_amdgcn_mfma_f32_16x16x32_bf16(
                    w1a[mt], b1f, (f32x4){0.f, 0.f, 0.f, 0.f}, 0, 0, 0);
                float v0 = fmaxf(c1[0], 0.f), v1 = fmaxf(c1[1], 0.f);
                float v2 = fmaxf(c1[2], 0.f), v3 = fmaxf(c1[3], 0.f);
                int f0 = (mt * 16 + h * 4) ^ sw;
                *(int2v*)&y1b[wv][pl][f0] = (int2v){(int)cvtpk(v0, v1), (int)cvtpk(v2, v3)};
            }

            short8v b2f0 = *(const short8v*)&y1b[wv][pl][(h * 8) ^ sw];
            short8v b2f1 = *(const short8v*)&y1b[wv][pl][(32 + h * 8) ^ sw];
            float y2[4][4];
#pragma unroll
            for (int mt2 = 0; mt2 < 4; ++mt2) {
                f32x4 c2 = b2v[mt2];
                c2 = __builtin_amdgcn_mfma_f32_16x16x32_bf16(w2a[mt2][0], b2f0, c2, 0, 0, 0);
                c2 = __builtin_amdgcn_mfma_f32_16x16x32_bf16(w2a[mt2][1], b2f1, c2, 0, 0, 0);
                y2[mt2][0] = fmaxf(c2[0], 0.f);
                y2[mt2][1] = fmaxf(c2[1], 0.f);
                y2[mt2][2] = fmaxf(c2[2], 0.f);
                y2[mt2][3] = fmaxf(c2[3], 0.f);
            }

            // LN64
            float s = 0.f, q = 0.f;
#pragma unroll
            for (int mt2 = 0; mt2 < 4; ++mt2)
#pragma unroll
                for (int r = 0; r < 4; ++r) { s += y2[mt2][r]; q = fmaf(y2[mt2][r], y2[mt2][r], q); }
            s += __shfl_xor(s, 16, 64); s += __shfl_xor(s, 32, 64);
            q += __shfl_xor(q, 16, 64); q += __shfl_xor(q, 32, 64);
            float m2  = s * (1.0f / 64.0f);
            float v2_ = fmaxf(q * (1.0f / 64.0f) - m2 * m2, 0.f);
            float rs2 = rsqrtf(v2_ + 1e-5f);

            bool valid = (tt0 + pl) < 52;
#pragma unroll
            for (int mt2 = 0; mt2 < 4; ++mt2)
#pragma unroll
                for (int r = 0; r < 4; ++r) {
                    float z = fmaf((y2[mt2][r] - m2) * rs2, lw4[mt2][r], lb4[mt2][r]);
                    y2[mt2][r] = valid ? z : 0.f;
                }

            // z2 pairs -> zP (swizzled)
#pragma unroll
            for (int mt2 = 0; mt2 < 4; ++mt2)
#pragma unroll
                for (int rp = 0; rp < 2; ++rp) {
                    int g0 = mt2 * 16 + h * 4 + rp * 2;
                    int k2 = pl * 128 + g0 * 2;
                    int byte = (px << 11) + ((k2 ^ (((k2 >> 7) & 7) << 4)) ^ nswp);
                    *(unsigned*)((char*)zP + byte) = cvtpk(y2[mt2][rp * 2], y2[mt2][rp * 2 + 1]);
                }
        }
        __syncthreads();

        // ---- fc1 MFMA: wave covers chunks wv*4..wv*4+3 (K=128 of 1024) ----
        const int4v* abase = aimg + (t * 32 + wv * 4) * 64 + lane;
        int nswr = nswz(pl);
#pragma unroll
        for (int cc = 0; cc < 4; ++cc) {
            int c = wv * 4 + cc;
            short8v afrag = __builtin_bit_cast(short8v, abase[cc * 64]);
            int k2 = c * 64 + h * 16;
            int byte = (pl << 11) + ((k2 ^ (((k2 >> 7) & 7) << 4)) ^ nswr);
            short8v bfrag = *(const short8v*)((const char*)zP + byte);
            dacc = __builtin_amdgcn_mfma_f32_16x16x32_bf16(afrag, bfrag, dacc, 0, 0, 0);
        }
        __syncthreads();
    }

    // ---- epilogue: cross-wave reduce + fc2 + tanh (16 pixels) ----
    *(f32x4*)&dred[wv][pl][h * 4] = dacc;
    __syncthreads();
    if (tid < 256) {
        int n4 = tid >> 4, j = tid & 15;
        float hj = 0.f;
#pragma unroll
        for (int w = 0; w < 8; ++w) hj += dred[w][n4][j];
        hj = fmaxf(hj + fc1b[j], 0.f);
        float th[5];
#pragma unroll
        for (int d = 0; d < 5; ++d) {
            float sd = hj * fc2w[j * 5 + d];
            sd += __shfl_xor(sd, 1, 64); sd += __shfl_xor(sd, 2, 64);
            sd += __shfl_xor(sd, 4, 64); sd += __shfl_xor(sd, 8, 64);
            th[d] = sd;
        }
        if (j < 5) outtheta[(base16 + n4) * TD + j] = tanhf(th[j] + fc2b[j]);
    }
}

// ---------------------------------------------------------------------------
extern "C" void kernel_launch(void* const* d_in, const int* in_sizes, int n_in,
                              void* d_out, int out_size, void* d_ws, size_t ws_size,
                              hipStream_t stream) {
    const float* x     = (const float*)d_in[0];
    const float* thraw = (const float*)d_in[1];
    const float* lniw  = (const float*)d_in[2];
    const float* lnib  = (const float*)d_in[3];
    const float* w1c   = (const float*)d_in[4];
    const float* b1c   = (const float*)d_in[5];
    const float* w2c   = (const float*)d_in[6];
    const float* b2c   = (const float*)d_in[7];
    const float* lncw  = (const float*)d_in[8];
    const float* lncb  = (const float*)d_in[9];
    const float* fc1w  = (const float*)d_in[10];
    const float* fc1b  = (const float*)d_in[11];
    const float* fc2w  = (const float*)d_in[12];
    const float* fc2b  = (const float*)d_in[13];
    float* out  = (float*)d_out;
    float* ws   = (float*)d_ws;
    float* Bf   = ws + WS_BF;
    int4v* wimg = (int4v*)(ws + WS_WIMG);
    int4v* aimg = (int4v*)(ws + WS_AIMG);
    float* xp   = ws + WS_XPIX;
    int use_xp  = (ws_size >= (size_t)(WS_XPIX + NP * CCH * TT) * 4) ? 1 : 0;
    int npre    = use_xp ? (65 + 2304) : 65;

    hipLaunchKernelGGL(k_pre, dim3(npre), dim3(256), 0, stream,
                       lniw, lnib, w1c, b1c, w2c, fc1w, x, Bf, wimg, aimg, xp, use_xp);
    hipLaunchKernelGGL(k_cpab, dim3((NP * TT) / 256), dim3(256), 0, stream,
                       x, xp, use_xp, thraw, Bf, 0.5f, out + OUT1, out + OUT3, 1);
    hipLaunchKernelGGL(k_loc, dim3(NP / 16), dim3(512), 0, stream,
                       x, out + OUT1, wimg, aimg, b2c, lncw, lncb,
                       fc1b, fc2w, fc2b, out + OUT2);
    hipLaunchKernelGGL(k_cpab, dim3((NP * TT) / 256), dim3(256), 0, stream,
                       x, xp, use_xp, out + OUT2, Bf, 1.0f, out + OUT0, out, 0);
}

// Round 11
// 235.584 us; speedup vs baseline: 1.5081x; 1.5081x over previous
//
#include <hip/hip_runtime.h>
#include <math.h>

// Problem constants
#define TT   52        // time steps
#define BBAT 4         // batch
#define CCH  9         // input channels
#define HWP  4096      // 64*64 pixels per image
#define FF   64        // features
#define NP   16384     // b*h*w pixels
#define TD   5         // theta dim
#define NCC  6         // tessellation cells
#define TSTRIDE 147456 // b*c*h*w (stride of t in x, floats)

// output offsets (floats)
#define OUT0 0
#define OUT1 (NP*CCH*TT)        // x_shift_pix
#define OUT2 (2*NP*CCH*TT)      // theta_pred
#define OUT3 (OUT2 + NP*TD)     // theta_shift

// workspace offsets (floats)
#define WS_BF    0      // 60 floats: CPAB basis
#define WS_WIMG  1024   // 12*64 int4: w1a/w2a fragment image
#define WS_AIMG  4096   // 8*32*64 int4 = 65536 floats: fc1w A-fragment image
#define WS_XPIX  69632  // NP*CCH*TT floats: x pixel-major [n][c][t] (optional)

typedef __attribute__((ext_vector_type(8)))  short short8v;
typedef __attribute__((ext_vector_type(4)))  float f32x4;
typedef __attribute__((ext_vector_type(4)))  int   int4v;
typedef __attribute__((ext_vector_type(2)))  int   int2v;

// RNE f32->bf16 bits, packed pair (scalar fallback, prep kernels)
__device__ __forceinline__ unsigned bfb(float f) {
    unsigned x = __builtin_bit_cast(unsigned, f);
    return (x + 0x7fffu + ((x >> 16) & 1u)) >> 16;
}
__device__ __forceinline__ unsigned pk2(float a, float b) {
    return bfb(a) | (bfb(b) << 16);
}
// HW packed convert (1 VALU op): D.lo = bf16(a), D.hi = bf16(b)
__device__ __forceinline__ unsigned cvtpk(float a, float b) {
    unsigned r;
    asm("v_cvt_pk_bf16_f32 %0, %1, %2" : "=v"(r) : "v"(a), "v"(b));
    return r;
}
// zP row-XOR helper
__device__ __forceinline__ int nswz(int n) {
    return (((n ^ (n >> 3)) & 1) << 6) | (((n >> 1) & 3) << 4);
}

// ---------------------------------------------------------------------------
// k_pre: merged prep. block 0: basis (wave 0) + conv fragments (wave 1);
// blocks 1..64: fc1w A-fragment image; blocks 65..2368: x -> xp transpose.
// ---------------------------------------------------------------------------
__global__ __launch_bounds__(256) void k_pre(
    const float* __restrict__ lniw, const float* __restrict__ lnib,
    const float* __restrict__ w1c,  const float* __restrict__ b1c,
    const float* __restrict__ w2c,  const float* __restrict__ fc1w,
    const float* __restrict__ x,
    float* __restrict__ Bout, int4v* __restrict__ wimg,
    int4v* __restrict__ aimg, float* __restrict__ xp, int use_xp)
{
    __shared__ float ld[52 * 65];
    int blk = blockIdx.x;
    int tid = threadIdx.x;

    if (blk == 0) {
        if (tid < 64) {
            // ---- basis: np.linalg.svd(L) null-space (dgesdd LQ path) ----
            int k = tid;
            double Acol[7], Vcol[7], Mcol[5];
#pragma unroll
            for (int r = 0; r < 7; r++) { Acol[r] = 0.0; Vcol[r] = 0.0; }
#pragma unroll
            for (int j = 0; j < 5; j++) Mcol[j] = 0.0;
            if (k < 12) {
#pragma unroll
                for (int j = 1; j < 6; j++) {
                    int r = j - 1;
                    double xj = (double)j / 6.0;
                    if (k == 2 * (j - 1))     Acol[r] = xj;
                    if (k == 2 * (j - 1) + 1) Acol[r] = 1.0;
                    if (k == 2 * j)           Acol[r] = -xj;
                    if (k == 2 * j + 1)       Acol[r] = -1.0;
                }
                if (k == 1)  Acol[5] = 1.0;
                if (k == 10) Acol[6] = 1.0;
                if (k == 11) Acol[6] = 1.0;
#pragma unroll
                for (int j = 0; j < 5; j++) Mcol[j] = (k == 7 + j) ? 1.0 : 0.0;
            }
            double tau[7];
#pragma unroll
            for (int i = 0; i < 7; i++) {
                double c = (k > i && k < 12) ? Acol[i] * Acol[i] : 0.0;
#pragma unroll
                for (int off = 1; off < 64; off <<= 1) c += __shfl_xor(c, off, 64);
                double alpha = __shfl(Acol[i], i, 64);
                double t_i, vk;
                if (c == 0.0) {
                    t_i = 0.0;
                    vk = (k == i) ? 1.0 : 0.0;
                } else {
                    double nrm  = sqrt(alpha * alpha + c);
                    double beta = (alpha >= 0.0) ? -nrm : nrm;  // Fortran SIGN
                    t_i = (beta - alpha) / beta;
                    double inv = 1.0 / (alpha - beta);
                    vk = (k == i) ? 1.0 : ((k > i && k < 12) ? Acol[i] * inv : 0.0);
                }
                tau[i]  = t_i;
                Vcol[i] = vk;
#pragma unroll
                for (int r = 0; r < 7; r++) {
                    if (r > i) {
                        double w = Acol[r] * vk;
#pragma unroll
                        for (int off = 1; off < 64; off <<= 1) w += __shfl_xor(w, off, 64);
                        Acol[r] -= t_i * w * vk;
                    }
                }
            }
#pragma unroll
            for (int i = 6; i >= 0; i--) {
#pragma unroll
                for (int j = 0; j < 5; j++) {
                    double w = Mcol[j] * Vcol[i];
#pragma unroll
                    for (int off = 1; off < 64; off <<= 1) w += __shfl_xor(w, off, 64);
                    Mcol[j] -= tau[i] * w * Vcol[i];
                }
            }
            if (k < 12) {
#pragma unroll
                for (int j = 0; j < 5; j++) Bout[k * 5 + j] = (float)Mcol[j];
            }
        } else if (tid < 128) {
            // ---- conv1/conv2 MFMA A-fragments -> wimg ----
            int lane = tid - 64;
            int pl = lane & 15, h = lane >> 4;
#pragma unroll
            for (int mt = 0; mt < 4; ++mt) {
                int f = mt * 16 + pl;
                float b0f = b1c[f];
#pragma unroll
                for (int c = 0; c < 9; ++c) b0f += lnib[c] * w1c[c * 64 + f];
                float v[8];
#pragma unroll
                for (int i = 0; i < 8; ++i) {
                    int c  = h * 8 + i;
                    int cc = c < 9 ? c : 8;
                    float lv = lniw[cc] * w1c[cc * 64 + f];
                    v[i] = (c < 9) ? lv : ((c == 9) ? b0f : 0.f);
                }
                wimg[mt * 64 + lane] = (int4v){(int)pk2(v[0],v[1]), (int)pk2(v[2],v[3]),
                                               (int)pk2(v[4],v[5]), (int)pk2(v[6],v[7])};
            }
#pragma unroll
            for (int mt2 = 0; mt2 < 4; ++mt2) {
                int g = mt2 * 16 + pl;
#pragma unroll
                for (int ks = 0; ks < 2; ++ks) {
                    float v[8];
#pragma unroll
                    for (int i = 0; i < 8; ++i) v[i] = w2c[(ks * 32 + h * 8 + i) * 64 + g];
                    wimg[(4 + mt2 * 2 + ks) * 64 + lane] =
                        (int4v){(int)pk2(v[0],v[1]), (int)pk2(v[2],v[3]),
                                (int)pk2(v[4],v[5]), (int)pk2(v[6],v[7])};
                }
            }
        }
    } else if (blk <= 64) {
        // ---- fc1w -> bf16 A-fragment image ----
        int gid  = (blk - 1) * 256 + tid;
        int lane = gid & 63;
        int tc   = gid >> 6;
        int t = tc >> 5, c = tc & 31;
        int bt = t >> 2, tt0 = (t & 3) << 4;
        int m = lane & 15, h = lane >> 4;
        float v[8];
#pragma unroll
        for (int i = 0; i < 8; ++i) {
            int k = c * 32 + h * 8 + i;
            int pos_l = k >> 6, g = k & 63;
            int tt = tt0 + pos_l;
            v[i] = (tt < 52) ? fc1w[(bt * 3328 + g * 52 + tt) * 16 + m] : 0.f;
        }
        aimg[gid] = (int4v){(int)pk2(v[0],v[1]), (int)pk2(v[2],v[3]),
                            (int)pk2(v[4],v[5]), (int)pk2(v[6],v[7])};
    } else if (use_xp) {
        // ---- x [t,b,c,h,w] -> xp [n][c][t], LDS-tiled transpose ----
        int b2 = blk - 65;
        int b = b2 / 576, rem = b2 % 576, c = rem >> 6, pt = rem & 63;
        int p0 = pt * 64;
        for (int idx = tid; idx < 52 * 64; idx += 256) {
            int t = idx >> 6, pp = idx & 63;
            ld[t * 65 + pp] = x[((t * BBAT + b) * CCH + c) * HWP + p0 + pp];
        }
        __syncthreads();
        int pn = tid >> 2, tq = tid & 3;
        float* dst = xp + (size_t)(b * HWP + p0 + pn) * (CCH * TT) + c * TT + tq * 13;
#pragma unroll
        for (int k = 0; k < 13; ++k) dst[k] = ld[(tq * 13 + k) * 65 + pn];
    }
}

// ---------------------------------------------------------------------------
// k_cpab: ODE + lerp (pixel-major xp when available); optionally also emits
// theta_shift = 0.5*raw (fused former k_theta_shift).
// ---------------------------------------------------------------------------
__global__ __launch_bounds__(256) void k_cpab(
    const float* __restrict__ x, const float* __restrict__ xp, int use_xp,
    const float* __restrict__ theta, const float* __restrict__ Bf,
    float scale, float* __restrict__ out,
    float* __restrict__ outts, int do_ts)
{
    int gid = blockIdx.x * blockDim.x + threadIdx.x;
    if (gid >= NP * TT) return;
    if (do_ts && gid < NP * TD) outts[gid] = 0.5f * theta[gid];
    int n = gid / TT, tt = gid % TT;

    float th[TD];
#pragma unroll
    for (int j = 0; j < TD; j++) th[j] = scale * theta[n * TD + j];

    float a[NCC], b[NCC];
#pragma unroll
    for (int i = 0; i < NCC; i++) {
        float aa = 0.f, bb = 0.f;
#pragma unroll
        for (int j = 0; j < TD; j++) {
            aa += th[j] * Bf[(2 * i) * TD + j];
            bb += th[j] * Bf[(2 * i + 1) * TD + j];
        }
        a[i] = aa; b[i] = bb;
    }

    float xc = (float)tt / 51.0f;
    for (int s = 0; s < 100; ++s) {
        float t6 = xc * 6.0f;
        float av = t6 < 1.f ? a[0] : t6 < 2.f ? a[1] : t6 < 3.f ? a[2]
                 : t6 < 4.f ? a[3] : t6 < 5.f ? a[4] : a[5];
        float bv = t6 < 1.f ? b[0] : t6 < 2.f ? b[1] : t6 < 3.f ? b[2]
                 : t6 < 4.f ? b[3] : t6 < 5.f ? b[4] : b[5];
        xc = xc + 0.01f * (av * xc + bv);
        xc = fminf(fmaxf(xc, 0.0f), 1.0f);
    }

    float pos = xc * 51.0f;
    int x0 = (int)floorf(pos);
    if (x0 < 0) x0 = 0;
    if (x0 > 50) x0 = 50;
    float w = pos - (float)x0;
    if (use_xp) {
        const float* row = xp + (size_t)n * (CCH * TT);
#pragma unroll
        for (int ch = 0; ch < CCH; ++ch) {
            float d0 = row[ch * TT + x0];
            float d1 = row[ch * TT + x0 + 1];
            out[n * (CCH * TT) + ch * TT + tt] = d0 * (1.0f - w) + d1 * w;
        }
    } else {
        int bb_ = n >> 12, p = n & 4095;
        int base0 = ((x0 * BBAT + bb_) * CCH) * HWP + p;
#pragma unroll
        for (int ch = 0; ch < CCH; ++ch) {
            float d0 = x[base0 + ch * HWP];
            float d1 = x[base0 + ch * HWP + TSTRIDE];
            out[n * (CCH * TT) + ch * TT + tt] = d0 * (1.0f - w) + d1 * w;
        }
    }
}

// ---------------------------------------------------------------------------
// k_loc (full-MFMA, 16 px / 8 waves / 512 threads).
// ROUND-11 FIX: __launch_bounds__(512, 2). The 2nd arg is CUDA-style
// min-BLOCKS-per-CU on this toolchain (round-10 evidence: (512,4) gave
// exactly 2048/32 = 64 VGPRs -> ~90 live regs spilled to scratch ->
// FETCH 408MB / WRITE 92MB). (512,2): 16 waves/CU, VGPR cap 128, no spill.
// ---------------------------------------------------------------------------
__global__ __launch_bounds__(512, 2) void k_loc(
    const float* __restrict__ x,     // [52,4,9,64,64]
    const float* __restrict__ xs,    // x_shift_pix [N,9,52]
    const int4v* __restrict__ wimg,  // conv fragment image
    const int4v* __restrict__ aimg,  // fc1w A-fragment image
    const float* __restrict__ b2c,
    const float* __restrict__ lncw,  const float* __restrict__ lncb,
    const float* __restrict__ fc1b,
    const float* __restrict__ fc2w,  const float* __restrict__ fc2b,
    float* __restrict__ outtheta)    // [N,5]
{
    __shared__ int4v          zcs[256];        // 4KB  zc lo-8 per (px,pos), swizzled
    __shared__ unsigned       zchs[256];       // 1KB  pk2(c8, bias)
    __shared__ unsigned short y1b[8][16][64];  // 16KB per-wave y1 tile
    __shared__ unsigned short zP[16][1024];    // 32KB z2 [px][k], swizzled
    __shared__ float          dred[8][16][16]; // 8KB  [wave][px][j]

    int tid    = threadIdx.x;
    int lane   = tid & 63;
    int wv     = tid >> 6;          // 0..7
    int base16 = blockIdx.x * 16;
    int bb_    = base16 >> 12, p0 = base16 & 4095;
    int pl     = lane & 15;
    int h      = lane >> 4;

    // ---- fragments (coalesced b128 from wimg) ----
    short8v w1a[4], w2a[4][2];
#pragma unroll
    for (int mt = 0; mt < 4; ++mt)
        w1a[mt] = __builtin_bit_cast(short8v, wimg[mt * 64 + lane]);
#pragma unroll
    for (int mt2 = 0; mt2 < 4; ++mt2)
#pragma unroll
        for (int ks = 0; ks < 2; ++ks)
            w2a[mt2][ks] = __builtin_bit_cast(short8v, wimg[(4 + mt2 * 2 + ks) * 64 + lane]);

    f32x4 b2v[4], lw4[4], lb4[4];
#pragma unroll
    for (int mt2 = 0; mt2 < 4; ++mt2) {
        b2v[mt2] = *(const f32x4*)(b2c  + mt2 * 16 + h * 4);
        lw4[mt2] = *(const f32x4*)(lncw + mt2 * 16 + h * 4);
        lb4[mt2] = *(const f32x4*)(lncb + mt2 * 16 + h * 4);
    }

    f32x4 dacc = (f32x4){0.f, 0.f, 0.f, 0.f};

    for (int t = 0; t < 8; ++t) {
        int bt = t >> 2, tt0 = (t & 3) << 4;

        // ---- LN9 stage (first 4 waves; one (px,pos) per thread) ----
        if (tid < 256) {
            int px, q;
            if (bt == 0) { px = tid & 15; q = tid >> 4; }   // lanes = px (coalesced)
            else         { px = tid >> 4; q = tid & 15; }   // lanes = tt (row-coalesced)
            int tt = tt0 + q;
            float zc[9], bias;
            if (tt < 52) {
                float xin[9];
                if (bt == 0) {
                    int base = ((tt * BBAT + bb_) * CCH) * HWP + p0 + px;
#pragma unroll
                    for (int c = 0; c < 9; ++c) xin[c] = x[base + c * HWP];
                } else {
                    int base = (base16 + px) * (CCH * TT) + tt;
#pragma unroll
                    for (int c = 0; c < 9; ++c) xin[c] = xs[base + c * TT];
                }
                float s1 = 0.f, s2 = 0.f;
#pragma unroll
                for (int c = 0; c < 9; ++c) { s1 += xin[c]; s2 += xin[c] * xin[c]; }
                float m  = s1 * (1.0f / 9.0f);
                float vv = fmaxf(s2 * (1.0f / 9.0f) - m * m, 0.f);
                float rs = rsqrtf(vv + 1e-5f);
#pragma unroll
                for (int c = 0; c < 9; ++c) zc[c] = (xin[c] - m) * rs;
                bias = 1.0f;
            } else {
#pragma unroll
                for (int c = 0; c < 9; ++c) zc[c] = 0.f;
                bias = 0.f;
            }
            zcs[px * 16 + (q ^ (px & 7))] =
                (int4v){(int)cvtpk(zc[0], zc[1]), (int)cvtpk(zc[2], zc[3]),
                        (int)cvtpk(zc[4], zc[5]), (int)cvtpk(zc[6], zc[7])};
            zchs[px * 16 + q] = cvtpk(zc[8], bias);
        }
        __syncthreads();

        // ---- conv: 2 pixels per wave ----
        int sw = (pl & 7) << 3;
#pragma unroll
        for (int sub = 0; sub < 2; ++sub) {
            int px = wv * 2 + sub;
            int nswp = nswz(px);

            short8v b1f;
            if (h == 1) {
                unsigned zv = zchs[px * 16 + pl];
                b1f = __builtin_bit_cast(short8v, (int4v){(int)zv, 0, 0, 0});
            } else {
                b1f = __builtin_bit_cast(short8v, zcs[px * 16 + (pl ^ (px & 7))]);
            }

#pragma unroll
            for (int mt = 0; mt < 4; ++mt) {
                f32x4 c1 = __builtin_amdgcn_mfma_f32_16x16x32_bf16(
                    w1a[mt], b1f, (f32x4){0.f, 0.f, 0.f, 0.f}, 0, 0, 0);
                float v0 = fmaxf(c1[0], 0.f), v1 = fmaxf(c1[1], 0.f);
                float v2 = fmaxf(c1[2], 0.f), v3 = fmaxf(c1[3], 0.f);
                int f0 = (mt * 16 + h * 4) ^ sw;
                *(int2v*)&y1b[wv][pl][f0] = (int2v){(int)cvtpk(v0, v1), (int)cvtpk(v2, v3)};
            }

            short8v b2f0 = *(const short8v*)&y1b[wv][pl][(h * 8) ^ sw];
            short8v b2f1 = *(const short8v*)&y1b[wv][pl][(32 + h * 8) ^ sw];
            float y2[4][4];
#pragma unroll
            for (int mt2 = 0; mt2 < 4; ++mt2) {
                f32x4 c2 = b2v[mt2];
                c2 = __builtin_amdgcn_mfma_f32_16x16x32_bf16(w2a[mt2][0], b2f0, c2, 0, 0, 0);
                c2 = __builtin_amdgcn_mfma_f32_16x16x32_bf16(w2a[mt2][1], b2f1, c2, 0, 0, 0);
                y2[mt2][0] = fmaxf(c2[0], 0.f);
                y2[mt2][1] = fmaxf(c2[1], 0.f);
                y2[mt2][2] = fmaxf(c2[2], 0.f);
                y2[mt2][3] = fmaxf(c2[3], 0.f);
            }

            // LN64
            float s = 0.f, q = 0.f;
#pragma unroll
            for (int mt2 = 0; mt2 < 4; ++mt2)
#pragma unroll
                for (int r = 0; r < 4; ++r) { s += y2[mt2][r]; q = fmaf(y2[mt2][r], y2[mt2][r], q); }
            s += __shfl_xor(s, 16, 64); s += __shfl_xor(s, 32, 64);
            q += __shfl_xor(q, 16, 64); q += __shfl_xor(q, 32, 64);
            float m2  = s * (1.0f / 64.0f);
            float v2_ = fmaxf(q * (1.0f / 64.0f) - m2 * m2, 0.f);
            float rs2 = rsqrtf(v2_ + 1e-5f);

            bool valid = (tt0 + pl) < 52;
#pragma unroll
            for (int mt2 = 0; mt2 < 4; ++mt2)
#pragma unroll
                for (int r = 0; r < 4; ++r) {
                    float z = fmaf((y2[mt2][r] - m2) * rs2, lw4[mt2][r], lb4[mt2][r]);
                    y2[mt2][r] = valid ? z : 0.f;
                }

            // z2 pairs -> zP (swizzled)
#pragma unroll
            for (int mt2 = 0; mt2 < 4; ++mt2)
#pragma unroll
                for (int rp = 0; rp < 2; ++rp) {
                    int g0 = mt2 * 16 + h * 4 + rp * 2;
                    int k2 = pl * 128 + g0 * 2;
                    int byte = (px << 11) + ((k2 ^ (((k2 >> 7) & 7) << 4)) ^ nswp);
                    *(unsigned*)((char*)zP + byte) = cvtpk(y2[mt2][rp * 2], y2[mt2][rp * 2 + 1]);
                }
        }
        __syncthreads();

        // ---- fc1 MFMA: wave covers chunks wv*4..wv*4+3 (K=128 of 1024) ----
        const int4v* abase = aimg + (t * 32 + wv * 4) * 64 + lane;
        int nswr = nswz(pl);
#pragma unroll
        for (int cc = 0; cc < 4; ++cc) {
            int c = wv * 4 + cc;
            short8v afrag = __builtin_bit_cast(short8v, abase[cc * 64]);
            int k2 = c * 64 + h * 16;
            int byte = (pl << 11) + ((k2 ^ (((k2 >> 7) & 7) << 4)) ^ nswr);
            short8v bfrag = *(const short8v*)((const char*)zP + byte);
            dacc = __builtin_amdgcn_mfma_f32_16x16x32_bf16(afrag, bfrag, dacc, 0, 0, 0);
        }
        __syncthreads();
    }

    // ---- epilogue: cross-wave reduce + fc2 + tanh (16 pixels) ----
    *(f32x4*)&dred[wv][pl][h * 4] = dacc;
    __syncthreads();
    if (tid < 256) {
        int n4 = tid >> 4, j = tid & 15;
        float hj = 0.f;
#pragma unroll
        for (int w = 0; w < 8; ++w) hj += dred[w][n4][j];
        hj = fmaxf(hj + fc1b[j], 0.f);
        float th[5];
#pragma unroll
        for (int d = 0; d < 5; ++d) {
            float sd = hj * fc2w[j * 5 + d];
            sd += __shfl_xor(sd, 1, 64); sd += __shfl_xor(sd, 2, 64);
            sd += __shfl_xor(sd, 4, 64); sd += __shfl_xor(sd, 8, 64);
            th[d] = sd;
        }
        if (j < 5) outtheta[(base16 + n4) * TD + j] = tanhf(th[j] + fc2b[j]);
    }
}

// ---------------------------------------------------------------------------
extern "C" void kernel_launch(void* const* d_in, const int* in_sizes, int n_in,
                              void* d_out, int out_size, void* d_ws, size_t ws_size,
                              hipStream_t stream) {
    const float* x     = (const float*)d_in[0];
    const float* thraw = (const float*)d_in[1];
    const float* lniw  = (const float*)d_in[2];
    const float* lnib  = (const float*)d_in[3];
    const float* w1c   = (const float*)d_in[4];
    const float* b1c   = (const float*)d_in[5];
    const float* w2c   = (const float*)d_in[6];
    const float* b2c   = (const float*)d_in[7];
    const float* lncw  = (const float*)d_in[8];
    const float* lncb  = (const float*)d_in[9];
    const float* fc1w  = (const float*)d_in[10];
    const float* fc1b  = (const float*)d_in[11];
    const float* fc2w  = (const float*)d_in[12];
    const float* fc2b  = (const float*)d_in[13];
    float* out  = (float*)d_out;
    float* ws   = (float*)d_ws;
    float* Bf   = ws + WS_BF;
    int4v* wimg = (int4v*)(ws + WS_WIMG);
    int4v* aimg = (int4v*)(ws + WS_AIMG);
    float* xp   = ws + WS_XPIX;
    int use_xp  = (ws_size >= (size_t)(WS_XPIX + NP * CCH * TT) * 4) ? 1 : 0;
    int npre    = use_xp ? (65 + 2304) : 65;

    hipLaunchKernelGGL(k_pre, dim3(npre), dim3(256), 0, stream,
                       lniw, lnib, w1c, b1c, w2c, fc1w, x, Bf, wimg, aimg, xp, use_xp);
    hipLaunchKernelGGL(k_cpab, dim3((NP * TT) / 256), dim3(256), 0, stream,
                       x, xp, use_xp, thraw, Bf, 0.5f, out + OUT1, out + OUT3, 1);
    hipLaunchKernelGGL(k_loc, dim3(NP / 16), dim3(512), 0, stream,
                       x, out + OUT1, wimg, aimg, b2c, lncw, lncb,
                       fc1b, fc2w, fc2b, out + OUT2);
    hipLaunchKernelGGL(k_cpab, dim3((NP * TT) / 256), dim3(256), 0, stream,
                       x, xp, use_xp, out + OUT2, Bf, 1.0f, out + OUT0, out, 0);
}

// Round 12
// 229.923 us; speedup vs baseline: 1.5452x; 1.0246x over previous
//
#include <hip/hip_runtime.h>
#include <math.h>

// Problem constants
#define TT   52        // time steps
#define BBAT 4         // batch
#define CCH  9         // input channels
#define HWP  4096      // 64*64 pixels per image
#define FF   64        // features
#define NP   16384     // b*h*w pixels
#define TD   5         // theta dim
#define NCC  6         // tessellation cells
#define TSTRIDE 147456 // b*c*h*w (stride of t in x, floats)

// output offsets (floats)
#define OUT0 0
#define OUT1 (NP*CCH*TT)        // x_shift_pix
#define OUT2 (2*NP*CCH*TT)      // theta_pred
#define OUT3 (OUT2 + NP*TD)     // theta_shift

// workspace offsets (floats)
#define WS_BF    0      // 60 floats: CPAB basis
#define WS_WIMG  1024   // 12*64 int4: w1a/w2a fragment image
#define WS_AIMG  4096   // 8*32*64 int4 = 65536 floats: fc1w A-fragment image
#define WS_XPIX  69632  // NP*CCH*TT floats: x pixel-major [n][c][t] (optional)

typedef __attribute__((ext_vector_type(8)))  short short8v;
typedef __attribute__((ext_vector_type(4)))  float f32x4;
typedef __attribute__((ext_vector_type(4)))  int   int4v;
typedef __attribute__((ext_vector_type(2)))  int   int2v;

// RNE f32->bf16 bits, packed pair (scalar fallback, prep kernels)
__device__ __forceinline__ unsigned bfb(float f) {
    unsigned x = __builtin_bit_cast(unsigned, f);
    return (x + 0x7fffu + ((x >> 16) & 1u)) >> 16;
}
__device__ __forceinline__ unsigned pk2(float a, float b) {
    return bfb(a) | (bfb(b) << 16);
}
// HW packed convert (1 VALU op): D.lo = bf16(a), D.hi = bf16(b)
__device__ __forceinline__ unsigned cvtpk(float a, float b) {
    unsigned r;
    asm("v_cvt_pk_bf16_f32 %0, %1, %2" : "=v"(r) : "v"(a), "v"(b));
    return r;
}
// zP row-XOR helper
__device__ __forceinline__ int nswz(int n) {
    return (((n ^ (n >> 3)) & 1) << 6) | (((n >> 1) & 3) << 4);
}

// ---------------------------------------------------------------------------
// k_pre: merged prep. block 0: basis (wave 0) + conv fragments (wave 1);
// blocks 1..64: fc1w A-fragment image; blocks 65..2368: x -> xp transpose.
// ---------------------------------------------------------------------------
__global__ __launch_bounds__(256) void k_pre(
    const float* __restrict__ lniw, const float* __restrict__ lnib,
    const float* __restrict__ w1c,  const float* __restrict__ b1c,
    const float* __restrict__ w2c,  const float* __restrict__ fc1w,
    const float* __restrict__ x,
    float* __restrict__ Bout, int4v* __restrict__ wimg,
    int4v* __restrict__ aimg, float* __restrict__ xp, int use_xp)
{
    __shared__ float ld[52 * 65];
    int blk = blockIdx.x;
    int tid = threadIdx.x;

    if (blk == 0) {
        if (tid < 64) {
            // ---- basis: np.linalg.svd(L) null-space (dgesdd LQ path) ----
            int k = tid;
            double Acol[7], Vcol[7], Mcol[5];
#pragma unroll
            for (int r = 0; r < 7; r++) { Acol[r] = 0.0; Vcol[r] = 0.0; }
#pragma unroll
            for (int j = 0; j < 5; j++) Mcol[j] = 0.0;
            if (k < 12) {
#pragma unroll
                for (int j = 1; j < 6; j++) {
                    int r = j - 1;
                    double xj = (double)j / 6.0;
                    if (k == 2 * (j - 1))     Acol[r] = xj;
                    if (k == 2 * (j - 1) + 1) Acol[r] = 1.0;
                    if (k == 2 * j)           Acol[r] = -xj;
                    if (k == 2 * j + 1)       Acol[r] = -1.0;
                }
                if (k == 1)  Acol[5] = 1.0;
                if (k == 10) Acol[6] = 1.0;
                if (k == 11) Acol[6] = 1.0;
#pragma unroll
                for (int j = 0; j < 5; j++) Mcol[j] = (k == 7 + j) ? 1.0 : 0.0;
            }
            double tau[7];
#pragma unroll
            for (int i = 0; i < 7; i++) {
                double c = (k > i && k < 12) ? Acol[i] * Acol[i] : 0.0;
#pragma unroll
                for (int off = 1; off < 64; off <<= 1) c += __shfl_xor(c, off, 64);
                double alpha = __shfl(Acol[i], i, 64);
                double t_i, vk;
                if (c == 0.0) {
                    t_i = 0.0;
                    vk = (k == i) ? 1.0 : 0.0;
                } else {
                    double nrm  = sqrt(alpha * alpha + c);
                    double beta = (alpha >= 0.0) ? -nrm : nrm;  // Fortran SIGN
                    t_i = (beta - alpha) / beta;
                    double inv = 1.0 / (alpha - beta);
                    vk = (k == i) ? 1.0 : ((k > i && k < 12) ? Acol[i] * inv : 0.0);
                }
                tau[i]  = t_i;
                Vcol[i] = vk;
#pragma unroll
                for (int r = 0; r < 7; r++) {
                    if (r > i) {
                        double w = Acol[r] * vk;
#pragma unroll
                        for (int off = 1; off < 64; off <<= 1) w += __shfl_xor(w, off, 64);
                        Acol[r] -= t_i * w * vk;
                    }
                }
            }
#pragma unroll
            for (int i = 6; i >= 0; i--) {
#pragma unroll
                for (int j = 0; j < 5; j++) {
                    double w = Mcol[j] * Vcol[i];
#pragma unroll
                    for (int off = 1; off < 64; off <<= 1) w += __shfl_xor(w, off, 64);
                    Mcol[j] -= tau[i] * w * Vcol[i];
                }
            }
            if (k < 12) {
#pragma unroll
                for (int j = 0; j < 5; j++) Bout[k * 5 + j] = (float)Mcol[j];
            }
        } else if (tid < 128) {
            // ---- conv1/conv2 MFMA A-fragments -> wimg ----
            int lane = tid - 64;
            int pl = lane & 15, h = lane >> 4;
#pragma unroll
            for (int mt = 0; mt < 4; ++mt) {
                int f = mt * 16 + pl;
                float b0f = b1c[f];
#pragma unroll
                for (int c = 0; c < 9; ++c) b0f += lnib[c] * w1c[c * 64 + f];
                float v[8];
#pragma unroll
                for (int i = 0; i < 8; ++i) {
                    int c  = h * 8 + i;
                    int cc = c < 9 ? c : 8;
                    float lv = lniw[cc] * w1c[cc * 64 + f];
                    v[i] = (c < 9) ? lv : ((c == 9) ? b0f : 0.f);
                }
                wimg[mt * 64 + lane] = (int4v){(int)pk2(v[0],v[1]), (int)pk2(v[2],v[3]),
                                               (int)pk2(v[4],v[5]), (int)pk2(v[6],v[7])};
            }
#pragma unroll
            for (int mt2 = 0; mt2 < 4; ++mt2) {
                int g = mt2 * 16 + pl;
#pragma unroll
                for (int ks = 0; ks < 2; ++ks) {
                    float v[8];
#pragma unroll
                    for (int i = 0; i < 8; ++i) v[i] = w2c[(ks * 32 + h * 8 + i) * 64 + g];
                    wimg[(4 + mt2 * 2 + ks) * 64 + lane] =
                        (int4v){(int)pk2(v[0],v[1]), (int)pk2(v[2],v[3]),
                                (int)pk2(v[4],v[5]), (int)pk2(v[6],v[7])};
                }
            }
        }
    } else if (blk <= 64) {
        // ---- fc1w -> bf16 A-fragment image (pad positions zeroed) ----
        int gid  = (blk - 1) * 256 + tid;
        int lane = gid & 63;
        int tc   = gid >> 6;
        int t = tc >> 5, c = tc & 31;
        int bt = t >> 2, tt0 = (t & 3) << 4;
        int m = lane & 15, h = lane >> 4;
        float v[8];
#pragma unroll
        for (int i = 0; i < 8; ++i) {
            int k = c * 32 + h * 8 + i;
            int pos_l = k >> 6, g = k & 63;
            int tt = tt0 + pos_l;
            v[i] = (tt < 52) ? fc1w[(bt * 3328 + g * 52 + tt) * 16 + m] : 0.f;
        }
        aimg[gid] = (int4v){(int)pk2(v[0],v[1]), (int)pk2(v[2],v[3]),
                            (int)pk2(v[4],v[5]), (int)pk2(v[6],v[7])};
    } else if (use_xp) {
        // ---- x [t,b,c,h,w] -> xp [n][c][t], LDS-tiled transpose ----
        int b2 = blk - 65;
        int b = b2 / 576, rem = b2 % 576, c = rem >> 6, pt = rem & 63;
        int p0 = pt * 64;
        for (int idx = tid; idx < 52 * 64; idx += 256) {
            int t = idx >> 6, pp = idx & 63;
            ld[t * 65 + pp] = x[((t * BBAT + b) * CCH + c) * HWP + p0 + pp];
        }
        __syncthreads();
        int pn = tid >> 2, tq = tid & 3;
        float* dst = xp + (size_t)(b * HWP + p0 + pn) * (CCH * TT) + c * TT + tq * 13;
#pragma unroll
        for (int k = 0; k < 13; ++k) dst[k] = ld[(tq * 13 + k) * 65 + pn];
    }
}

// ---------------------------------------------------------------------------
// k_cpab: ODE + lerp (pixel-major xp when available); optionally also emits
// theta_shift = 0.5*raw.
// ---------------------------------------------------------------------------
__global__ __launch_bounds__(256) void k_cpab(
    const float* __restrict__ x, const float* __restrict__ xp, int use_xp,
    const float* __restrict__ theta, const float* __restrict__ Bf,
    float scale, float* __restrict__ out,
    float* __restrict__ outts, int do_ts)
{
    int gid = blockIdx.x * blockDim.x + threadIdx.x;
    if (gid >= NP * TT) return;
    if (do_ts && gid < NP * TD) outts[gid] = 0.5f * theta[gid];
    int n = gid / TT, tt = gid % TT;

    float th[TD];
#pragma unroll
    for (int j = 0; j < TD; j++) th[j] = scale * theta[n * TD + j];

    float a[NCC], b[NCC];
#pragma unroll
    for (int i = 0; i < NCC; i++) {
        float aa = 0.f, bb = 0.f;
#pragma unroll
        for (int j = 0; j < TD; j++) {
            aa += th[j] * Bf[(2 * i) * TD + j];
            bb += th[j] * Bf[(2 * i + 1) * TD + j];
        }
        a[i] = aa; b[i] = bb;
    }

    float xc = (float)tt / 51.0f;
    for (int s = 0; s < 100; ++s) {
        float t6 = xc * 6.0f;
        float av = t6 < 1.f ? a[0] : t6 < 2.f ? a[1] : t6 < 3.f ? a[2]
                 : t6 < 4.f ? a[3] : t6 < 5.f ? a[4] : a[5];
        float bv = t6 < 1.f ? b[0] : t6 < 2.f ? b[1] : t6 < 3.f ? b[2]
                 : t6 < 4.f ? b[3] : t6 < 5.f ? b[4] : b[5];
        xc = xc + 0.01f * (av * xc + bv);
        xc = fminf(fmaxf(xc, 0.0f), 1.0f);
    }

    float pos = xc * 51.0f;
    int x0 = (int)floorf(pos);
    if (x0 < 0) x0 = 0;
    if (x0 > 50) x0 = 50;
    float w = pos - (float)x0;
    if (use_xp) {
        const float* row = xp + (size_t)n * (CCH * TT);
#pragma unroll
        for (int ch = 0; ch < CCH; ++ch) {
            float d0 = row[ch * TT + x0];
            float d1 = row[ch * TT + x0 + 1];
            out[n * (CCH * TT) + ch * TT + tt] = d0 * (1.0f - w) + d1 * w;
        }
    } else {
        int bb_ = n >> 12, p = n & 4095;
        int base0 = ((x0 * BBAT + bb_) * CCH) * HWP + p;
#pragma unroll
        for (int ch = 0; ch < CCH; ++ch) {
            float d0 = x[base0 + ch * HWP];
            float d1 = x[base0 + ch * HWP + TSTRIDE];
            out[n * (CCH * TT) + ch * TT + tt] = d0 * (1.0f - w) + d1 * w;
        }
    }
}

// ---------------------------------------------------------------------------
// k_loc (full-MFMA, 16 px / 8 waves / 512 threads).
// Round-12 deltas vs round 11:
//  - pad-masking removed: aimg has zero A-columns at pad positions, so the
//    per-sub `valid ? z : 0` cndmask chain was dead work (pads give finite z).
//  - dred aliased into zP (epilogue-only; end-of-loop barrier orders reuse):
//    declared LDS 61 -> 53KB => 3 blocks/CU fit.
//  - __launch_bounds__(512, 3): 3 blocks/CU (24 waves), VGPR cap 85 (was 88
//    used @ cap 128; compiler must shave ~3). WRITE_SIZE adjudicates spills.
// ---------------------------------------------------------------------------
__global__ __launch_bounds__(512, 3) void k_loc(
    const float* __restrict__ x,     // [52,4,9,64,64]
    const float* __restrict__ xs,    // x_shift_pix [N,9,52]
    const int4v* __restrict__ wimg,  // conv fragment image
    const int4v* __restrict__ aimg,  // fc1w A-fragment image
    const float* __restrict__ b2c,
    const float* __restrict__ lncw,  const float* __restrict__ lncb,
    const float* __restrict__ fc1b,
    const float* __restrict__ fc2w,  const float* __restrict__ fc2b,
    float* __restrict__ outtheta)    // [N,5]
{
    __shared__ int4v          zcs[256];        // 4KB  zc lo-8 per (px,pos), swizzled
    __shared__ unsigned       zchs[256];       // 1KB  pk2(c8, bias)
    __shared__ unsigned short y1b[8][16][64];  // 16KB per-wave y1 tile
    __shared__ unsigned short zP[16][1024];    // 32KB z2 [px][k]; epilogue: dred alias

    int tid    = threadIdx.x;
    int lane   = tid & 63;
    int wv     = tid >> 6;          // 0..7
    int base16 = blockIdx.x * 16;
    int bb_    = base16 >> 12, p0 = base16 & 4095;
    int pl     = lane & 15;
    int h      = lane >> 4;

    // ---- fragments (coalesced b128 from wimg) ----
    short8v w1a[4], w2a[4][2];
#pragma unroll
    for (int mt = 0; mt < 4; ++mt)
        w1a[mt] = __builtin_bit_cast(short8v, wimg[mt * 64 + lane]);
#pragma unroll
    for (int mt2 = 0; mt2 < 4; ++mt2)
#pragma unroll
        for (int ks = 0; ks < 2; ++ks)
            w2a[mt2][ks] = __builtin_bit_cast(short8v, wimg[(4 + mt2 * 2 + ks) * 64 + lane]);

    f32x4 b2v[4], lw4[4], lb4[4];
#pragma unroll
    for (int mt2 = 0; mt2 < 4; ++mt2) {
        b2v[mt2] = *(const f32x4*)(b2c  + mt2 * 16 + h * 4);
        lw4[mt2] = *(const f32x4*)(lncw + mt2 * 16 + h * 4);
        lb4[mt2] = *(const f32x4*)(lncb + mt2 * 16 + h * 4);
    }

    f32x4 dacc = (f32x4){0.f, 0.f, 0.f, 0.f};

    for (int t = 0; t < 8; ++t) {
        int bt = t >> 2, tt0 = (t & 3) << 4;

        // ---- LN9 stage (first 4 waves; one (px,pos) per thread) ----
        if (tid < 256) {
            int px, q;
            if (bt == 0) { px = tid & 15; q = tid >> 4; }   // lanes = px (coalesced)
            else         { px = tid >> 4; q = tid & 15; }   // lanes = tt (row-coalesced)
            int tt = tt0 + q;
            float zc[9], bias;
            if (tt < 52) {
                float xin[9];
                if (bt == 0) {
                    int base = ((tt * BBAT + bb_) * CCH) * HWP + p0 + px;
#pragma unroll
                    for (int c = 0; c < 9; ++c) xin[c] = x[base + c * HWP];
                } else {
                    int base = (base16 + px) * (CCH * TT) + tt;
#pragma unroll
                    for (int c = 0; c < 9; ++c) xin[c] = xs[base + c * TT];
                }
                float s1 = 0.f, s2 = 0.f;
#pragma unroll
                for (int c = 0; c < 9; ++c) { s1 += xin[c]; s2 += xin[c] * xin[c]; }
                float m  = s1 * (1.0f / 9.0f);
                float vv = fmaxf(s2 * (1.0f / 9.0f) - m * m, 0.f);
                float rs = rsqrtf(vv + 1e-5f);
#pragma unroll
                for (int c = 0; c < 9; ++c) zc[c] = (xin[c] - m) * rs;
                bias = 1.0f;
            } else {
#pragma unroll
                for (int c = 0; c < 9; ++c) zc[c] = 0.f;
                bias = 0.f;
            }
            zcs[px * 16 + (q ^ (px & 7))] =
                (int4v){(int)cvtpk(zc[0], zc[1]), (int)cvtpk(zc[2], zc[3]),
                        (int)cvtpk(zc[4], zc[5]), (int)cvtpk(zc[6], zc[7])};
            zchs[px * 16 + q] = cvtpk(zc[8], bias);
        }
        __syncthreads();

        // ---- conv: 2 pixels per wave ----
        int sw = (pl & 7) << 3;
#pragma unroll
        for (int sub = 0; sub < 2; ++sub) {
            int px = wv * 2 + sub;
            int nswp = nswz(px);

            short8v b1f;
            if (h == 1) {
                unsigned zv = zchs[px * 16 + pl];
                b1f = __builtin_bit_cast(short8v, (int4v){(int)zv, 0, 0, 0});
            } else {
                b1f = __builtin_bit_cast(short8v, zcs[px * 16 + (pl ^ (px & 7))]);
            }

#pragma unroll
            for (int mt = 0; mt < 4; ++mt) {
                f32x4 c1 = __builtin_amdgcn_mfma_f32_16x16x32_bf16(
                    w1a[mt], b1f, (f32x4){0.f, 0.f, 0.f, 0.f}, 0, 0, 0);
                float v0 = fmaxf(c1[0], 0.f), v1 = fmaxf(c1[1], 0.f);
                float v2 = fmaxf(c1[2], 0.f), v3 = fmaxf(c1[3], 0.f);
                int f0 = (mt * 16 + h * 4) ^ sw;
                *(int2v*)&y1b[wv][pl][f0] = (int2v){(int)cvtpk(v0, v1), (int)cvtpk(v2, v3)};
            }

            short8v b2f0 = *(const short8v*)&y1b[wv][pl][(h * 8) ^ sw];
            short8v b2f1 = *(const short8v*)&y1b[wv][pl][(32 + h * 8) ^ sw];
            float y2[4][4];
#pragma unroll
            for (int mt2 = 0; mt2 < 4; ++mt2) {
                f32x4 c2 = b2v[mt2];
                c2 = __builtin_amdgcn_mfma_f32_16x16x32_bf16(w2a[mt2][0], b2f0, c2, 0, 0, 0);
                c2 = __builtin_amdgcn_mfma_f32_16x16x32_bf16(w2a[mt2][1], b2f1, c2, 0, 0, 0);
                y2[mt2][0] = fmaxf(c2[0], 0.f);
                y2[mt2][1] = fmaxf(c2[1], 0.f);
                y2[mt2][2] = fmaxf(c2[2], 0.f);
                y2[mt2][3] = fmaxf(c2[3], 0.f);
            }

            // LN64
            float s = 0.f, q = 0.f;
#pragma unroll
            for (int mt2 = 0; mt2 < 4; ++mt2)
#pragma unroll
                for (int r = 0; r < 4; ++r) { s += y2[mt2][r]; q = fmaf(y2[mt2][r], y2[mt2][r], q); }
            s += __shfl_xor(s, 16, 64); s += __shfl_xor(s, 32, 64);
            q += __shfl_xor(q, 16, 64); q += __shfl_xor(q, 32, 64);
            float m2  = s * (1.0f / 64.0f);
            float v2_ = fmaxf(q * (1.0f / 64.0f) - m2 * m2, 0.f);
            float rs2 = rsqrtf(v2_ + 1e-5f);

            // z2 (no pad-mask: aimg pad A-columns are zero; z stays finite)
#pragma unroll
            for (int mt2 = 0; mt2 < 4; ++mt2)
#pragma unroll
                for (int r = 0; r < 4; ++r)
                    y2[mt2][r] = fmaf((y2[mt2][r] - m2) * rs2, lw4[mt2][r], lb4[mt2][r]);

            // z2 pairs -> zP (swizzled)
#pragma unroll
            for (int mt2 = 0; mt2 < 4; ++mt2)
#pragma unroll
                for (int rp = 0; rp < 2; ++rp) {
                    int g0 = mt2 * 16 + h * 4 + rp * 2;
                    int k2 = pl * 128 + g0 * 2;
                    int byte = (px << 11) + ((k2 ^ (((k2 >> 7) & 7) << 4)) ^ nswp);
                    *(unsigned*)((char*)zP + byte) = cvtpk(y2[mt2][rp * 2], y2[mt2][rp * 2 + 1]);
                }
        }
        __syncthreads();

        // ---- fc1 MFMA: wave covers chunks wv*4..wv*4+3 (K=128 of 1024) ----
        const int4v* abase = aimg + (t * 32 + wv * 4) * 64 + lane;
        int nswr = nswz(pl);
#pragma unroll
        for (int cc = 0; cc < 4; ++cc) {
            int c = wv * 4 + cc;
            short8v afrag = __builtin_bit_cast(short8v, abase[cc * 64]);
            int k2 = c * 64 + h * 16;
            int byte = (pl << 11) + ((k2 ^ (((k2 >> 7) & 7) << 4)) ^ nswr);
            short8v bfrag = *(const short8v*)((const char*)zP + byte);
            dacc = __builtin_amdgcn_mfma_f32_16x16x32_bf16(afrag, bfrag, dacc, 0, 0, 0);
        }
        __syncthreads();
    }

    // ---- epilogue: cross-wave reduce (dred aliased into zP) + fc2 + tanh ----
    float* dred = (float*)zP;                     // [8][16][16] floats = 8KB
    *(f32x4*)&dred[(wv * 16 + pl) * 16 + h * 4] = dacc;
    __syncthreads();
    if (tid < 256) {
        int n4 = tid >> 4, j = tid & 15;
        float hj = 0.f;
#pragma unroll
        for (int w = 0; w < 8; ++w) hj += dred[(w * 16 + n4) * 16 + j];
        hj = fmaxf(hj + fc1b[j], 0.f);
        float th[5];
#pragma unroll
        for (int d = 0; d < 5; ++d) {
            float sd = hj * fc2w[j * 5 + d];
            sd += __shfl_xor(sd, 1, 64); sd += __shfl_xor(sd, 2, 64);
            sd += __shfl_xor(sd, 4, 64); sd += __shfl_xor(sd, 8, 64);
            th[d] = sd;
        }
        if (j < 5) outtheta[(base16 + n4) * TD + j] = tanhf(th[j] + fc2b[j]);
    }
}

// ---------------------------------------------------------------------------
extern "C" void kernel_launch(void* const* d_in, const int* in_sizes, int n_in,
                              void* d_out, int out_size, void* d_ws, size_t ws_size,
                              hipStream_t stream) {
    const float* x     = (const float*)d_in[0];
    const float* thraw = (const float*)d_in[1];
    const float* lniw  = (const float*)d_in[2];
    const float* lnib  = (const float*)d_in[3];
    const float* w1c   = (const float*)d_in[4];
    const float* b1c   = (const float*)d_in[5];
    const float* w2c   = (const float*)d_in[6];
    const float* b2c   = (const float*)d_in[7];
    const float* lncw  = (const float*)d_in[8];
    const float* lncb  = (const float*)d_in[9];
    const float* fc1w  = (const float*)d_in[10];
    const float* fc1b  = (const float*)d_in[11];
    const float* fc2w  = (const float*)d_in[12];
    const float* fc2b  = (const float*)d_in[13];
    float* out  = (float*)d_out;
    float* ws   = (float*)d_ws;
    float* Bf   = ws + WS_BF;
    int4v* wimg = (int4v*)(ws + WS_WIMG);
    int4v* aimg = (int4v*)(ws + WS_AIMG);
    float* xp   = ws + WS_XPIX;
    int use_xp  = (ws_size >= (size_t)(WS_XPIX + NP * CCH * TT) * 4) ? 1 : 0;
    int npre    = use_xp ? (65 + 2304) : 65;

    hipLaunchKernelGGL(k_pre, dim3(npre), dim3(256), 0, stream,
                       lniw, lnib, w1c, b1c, w2c, fc1w, x, Bf, wimg, aimg, xp, use_xp);
    hipLaunchKernelGGL(k_cpab, dim3((NP * TT) / 256), dim3(256), 0, stream,
                       x, xp, use_xp, thraw, Bf, 0.5f, out + OUT1, out + OUT3, 1);
    hipLaunchKernelGGL(k_loc, dim3(NP / 16), dim3(512), 0, stream,
                       x, out + OUT1, wimg, aimg, b2c, lncw, lncb,
                       fc1b, fc2w, fc2b, out + OUT2);
    hipLaunchKernelGGL(k_cpab, dim3((NP * TT) / 256), dim3(256), 0, stream,
                       x, xp, use_xp, out + OUT2, Bf, 1.0f, out + OUT0, out, 0);
}